// Round 1
// baseline (122.175 us; speedup 1.0000x reference)
//
#include <hip/hip_runtime.h>
#include <math.h>

#define FL 48

// ---------------- kernels ----------------

__global__ void k_zero(float* __restrict__ p, int n) {
  int i = blockIdx.x * blockDim.x + threadIdx.x;
  if (i < n) p[i] = 0.0f;
}

__global__ void k_count(const int* __restrict__ dst, float* __restrict__ cnt, int E) {
  int i = blockIdx.x * blockDim.x + threadIdx.x;
  if (i < E) atomicAdd(&cnt[dst[i]], 1.0f);
}

// scalar scatter: agg[dst[e]] += x[src[e]]
__global__ void k_scatter_s(const int* __restrict__ src, const int* __restrict__ dst,
                            const float* __restrict__ x, float* __restrict__ agg, int E) {
  int i = blockIdx.x * blockDim.x + threadIdx.x;
  if (i < E) atomicAdd(&agg[dst[i]], x[src[i]]);
}

// vector scatter: agg[dst[e]*48+c] += x[src[e]*48+c]
__global__ void k_scatter_v(const int* __restrict__ src, const int* __restrict__ dst,
                            const float* __restrict__ x, float* __restrict__ agg, int E) {
  int g = blockIdx.x * blockDim.x + threadIdx.x;
  if (g >= E * FL) return;
  int e = g / FL, c = g % FL;
  atomicAdd(&agg[dst[e] * FL + c], x[src[e] * FL + c]);
}

// SAGE level 1: C_in = 1
__global__ void k_sage1_node(const float* __restrict__ x, const float* __restrict__ agg,
                             const float* __restrict__ cnt, const float* __restrict__ Wl,
                             const float* __restrict__ bl, const float* __restrict__ Wr,
                             float* __restrict__ out, int N) {
  int g = blockIdx.x * blockDim.x + threadIdx.x;
  if (g >= N * FL) return;
  int n = g / FL, c = g % FL;
  float mean = agg[n] / fmaxf(cnt[n], 1.0f);
  out[g] = fmaxf(mean * Wl[c] + bl[c] + x[n] * Wr[c], 0.0f);
}

// SAGE 48->48: out[n][c] = relu(sum_ci mean[ci]*Wl[ci][c] + bl[c] + x[n][ci]*Wr[ci][c])
__global__ __launch_bounds__(256) void k_sage_node(
    const float* __restrict__ x, const float* __restrict__ agg, const float* __restrict__ cnt,
    const float* __restrict__ Wl, const float* __restrict__ bl, const float* __restrict__ Wr,
    float* __restrict__ out, int N) {
  __shared__ float sWl[FL * FL], sWr[FL * FL];
  for (int i = threadIdx.x; i < FL * FL; i += 256) { sWl[i] = Wl[i]; sWr[i] = Wr[i]; }
  __syncthreads();
  int g = blockIdx.x * 256 + threadIdx.x;
  if (g >= N * FL) return;
  int n = g / FL, c = g % FL;
  float rc = 1.0f / fmaxf(cnt[n], 1.0f);
  const float* xr = x + n * FL;
  const float* ar = agg + n * FL;
  float acc = bl[c];
  for (int ci = 0; ci < FL; ++ci)
    acc += (ar[ci] * rc) * sWl[ci * FL + c] + xr[ci] * sWr[ci * FL + c];
  out[g] = fmaxf(acc, 0.0f);
}

// 2x2 max pool on HxH grid (node-major (H*H,48) -> (H/2*H/2,48))
__global__ void k_pool(const float* __restrict__ x, float* __restrict__ y, int H) {
  int Ho = H / 2;
  int g = blockIdx.x * blockDim.x + threadIdx.x;
  int total = Ho * Ho * FL;
  if (g >= total) return;
  int c = g % FL, m = g / FL;
  int a = m / Ho, b = m % Ho;
  int r0 = 2 * a, c0 = 2 * b;
  float v = x[(r0 * H + c0) * FL + c];
  v = fmaxf(v, x[(r0 * H + c0 + 1) * FL + c]);
  v = fmaxf(v, x[((r0 + 1) * H + c0) * FL + c]);
  v = fmaxf(v, x[((r0 + 1) * H + c0 + 1) * FL + c]);
  y[m * FL + c] = v;
}

// per-channel mean and max over N nodes; one block per channel
__global__ void k_att_reduce(const float* __restrict__ x, int N,
                             float* __restrict__ mean_out, float* __restrict__ max_out) {
  int c = blockIdx.x;
  int t = threadIdx.x;
  float s = 0.0f, m = -INFINITY;
  for (int n = t; n < N; n += blockDim.x) {
    float v = x[n * FL + c];
    s += v; m = fmaxf(m, v);
  }
  __shared__ float ss[256], sm[256];
  ss[t] = s; sm[t] = m;
  __syncthreads();
  for (int o = 128; o > 0; o >>= 1) {
    if (t < o) { ss[t] += ss[t + o]; sm[t] = fmaxf(sm[t], sm[t + o]); }
    __syncthreads();
  }
  if (t == 0) { mean_out[c] = ss[0] / (float)N; max_out[c] = sm[0]; }
}

// att[co] = sigmoid(mean @ amW + amb + max @ axW + axb)
__global__ void k_att_vec(const float* __restrict__ mean, const float* __restrict__ mx,
                          const float* __restrict__ amW, const float* __restrict__ amb,
                          const float* __restrict__ axW, const float* __restrict__ axb,
                          float* __restrict__ att) {
  int co = threadIdx.x;
  if (co >= FL) return;
  float s = amb[co] + axb[co];
  for (int ci = 0; ci < FL; ++ci)
    s += mean[ci] * amW[ci * FL + co] + mx[ci] * axW[ci * FL + co];
  att[co] = 1.0f / (1.0f + expf(-s));
}

// s[n] = x[n,:] . cWl
__global__ void k_sdot(const float* __restrict__ x, const float* __restrict__ cWl,
                       float* __restrict__ s, int N) {
  int n = blockIdx.x * blockDim.x + threadIdx.x;
  if (n >= N) return;
  float a = 0.0f;
  for (int c = 0; c < FL; ++c) a += x[n * FL + c] * cWl[c];
  s[n] = a;
}

// in-place gate: x[n][c] *= (1 + att[c] + ch[n]); ch = sigmoid(aggS/cnt + cbl + x.cWr)
// one wave (64 lanes) per node
__global__ void k_gate(float* __restrict__ x, const float* __restrict__ att,
                       const float* __restrict__ aggS, const float* __restrict__ cnt,
                       const float* __restrict__ cWr, const float* __restrict__ cbl, int N) {
  int wid = (blockIdx.x * blockDim.x + threadIdx.x) / 64;
  int lane = threadIdx.x & 63;
  if (wid >= N) return;
  float xv = (lane < FL) ? x[wid * FL + lane] : 0.0f;
  float d = (lane < FL) ? xv * cWr[lane] : 0.0f;
  for (int o = 32; o > 0; o >>= 1) d += __shfl_xor(d, o);
  float pre = aggS[wid] / fmaxf(cnt[wid], 1.0f) + cbl[0] + d;
  float ch = 1.0f / (1.0f + expf(-pre));
  if (lane < FL) x[wid * FL + lane] = xv * (1.0f + att[lane] + ch);
}

// FC1 split-K: block b covers k in [b*128,(b+1)*128); thread t = output o
// input k = c*256 + n -> x4[n*48+c]
__global__ __launch_bounds__(256) void k_fc1(const float* __restrict__ x4,
                                             const float* __restrict__ W,
                                             float* __restrict__ acc) {
  __shared__ float xin[128];
  int b = blockIdx.x, t = threadIdx.x;
  int k0 = b * 128;
  if (t < 128) {
    int k = k0 + t;
    int c = k >> 8, n = k & 255;
    xin[t] = x4[n * FL + c];
  }
  __syncthreads();
  float a = 0.0f;
  for (int i = 0; i < 128; ++i) a += xin[i] * W[(size_t)(k0 + i) * 256 + t];
  atomicAdd(&acc[t], a);
}

// fuse fc1 bias+relu, fc2, log_softmax
__global__ void k_fc_final(const float* __restrict__ acc, const float* __restrict__ b1,
                           const float* __restrict__ W2, const float* __restrict__ b2,
                           float* __restrict__ out) {
  __shared__ float a[256];
  __shared__ float logits[10];
  int t = threadIdx.x;
  a[t] = fmaxf(acc[t] + b1[t], 0.0f);
  __syncthreads();
  if (t < 10) {
    float s = b2[t];
    for (int o = 0; o < 256; ++o) s += a[o] * W2[o * 10 + t];
    logits[t] = s;
  }
  __syncthreads();
  if (t == 0) {
    float m = logits[0];
    for (int j = 1; j < 10; ++j) m = fmaxf(m, logits[j]);
    float s = 0.0f;
    for (int j = 0; j < 10; ++j) s += expf(logits[j] - m);
    float ls = logf(s);
    for (int j = 0; j < 10; ++j) out[j] = logits[j] - m - ls;
  }
}

// ---------------- launch ----------------

static inline int cdiv(int a, int b) { return (a + b - 1) / b; }

extern "C" void kernel_launch(void* const* d_in, const int* in_sizes, int n_in,
                              void* d_out, int out_size, void* d_ws, size_t ws_size,
                              hipStream_t stream) {
  const float* x_image = (const float*)d_in[0];
  const int* e0 = (const int*)d_in[1];  // (2, 65536)
  const int* e1 = (const int*)d_in[2];  // (2, 16384)
  const int* e2 = (const int*)d_in[3];  // (2, 4096)
  const int* e3 = (const int*)d_in[4];  // (2, 1024)
  // d_in[5] = train (unused)
  const float* g1_Wl = (const float*)d_in[6];
  const float* g1_bl = (const float*)d_in[7];
  const float* g1_Wr = (const float*)d_in[8];
  const float* g2_Wl = (const float*)d_in[9];
  const float* g2_bl = (const float*)d_in[10];
  const float* g2_Wr = (const float*)d_in[11];
  const float* g3_Wl = (const float*)d_in[12];
  const float* g3_bl = (const float*)d_in[13];
  const float* g3_Wr = (const float*)d_in[14];
  const float* g4_Wl = (const float*)d_in[15];
  const float* g4_bl = (const float*)d_in[16];
  const float* g4_Wr = (const float*)d_in[17];
  // attention blocks: base 18 + (i-1)*7 : amW, amb, axW, axb, cWl, cbl, cWr
  const float* amW[3]; const float* amb[3]; const float* axW[3]; const float* axb[3];
  const float* cWl[3]; const float* cbl[3]; const float* cWr[3];
  for (int i = 0; i < 3; ++i) {
    int base = 18 + i * 7;
    amW[i] = (const float*)d_in[base + 0];
    amb[i] = (const float*)d_in[base + 1];
    axW[i] = (const float*)d_in[base + 2];
    axb[i] = (const float*)d_in[base + 3];
    cWl[i] = (const float*)d_in[base + 4];
    cbl[i] = (const float*)d_in[base + 5];
    cWr[i] = (const float*)d_in[base + 6];
  }
  const float* fc1_W = (const float*)d_in[46];
  const float* fc1_b = (const float*)d_in[47];
  const float* fc2_W = (const float*)d_in[48];
  const float* fc2_b = (const float*)d_in[49];
  float* out = (float*)d_out;

  const int N0 = 16384, E0 = 65536;
  const int N1 = 4096,  E1 = 16384;
  const int N2 = 1024,  E2 = 4096;
  const int N3 = 256,   E3 = 1024;

  // workspace layout (floats)
  float* f = (float*)d_ws;
  float* x1   = f;                 // 16384*48
  float* xp1  = x1  + N0 * FL;     // 4096*48
  float* x2   = xp1 + N1 * FL;     // 4096*48
  float* xp2  = x2  + N1 * FL;     // 1024*48
  float* x3   = xp2 + N2 * FL;     // 1024*48
  float* xp3  = x3  + N2 * FL;     // 256*48
  float* x4   = xp3 + N3 * FL;     // 256*48
  float* sdot = x4  + N3 * FL;     // 4096
  float* stats = sdot + N1;        // 192: mean[48], max[48], att[48]
  float* zbase = stats + 192;
  float* cnt0  = zbase;            // 16384
  float* cnt1  = cnt0 + N0;        // 4096
  float* cnt2  = cnt1 + N1;        // 1024
  float* cnt3  = cnt2 + N2;        // 256
  float* aggS0 = cnt3 + N3;        // 16384 (sage1)
  float* aggS1 = aggS0 + N0;       // 4096  (ch1)
  float* aggS2 = aggS1 + N1;       // 1024  (ch2)
  float* aggS3 = aggS2 + N2;       // 256   (ch3)
  float* aggC2 = aggS3 + N3;       // 4096*48 (sage2)
  float* aggC3 = aggC2 + N1 * FL;  // 1024*48 (sage3)
  float* aggC4 = aggC3 + N2 * FL;  // 256*48  (sage4)
  float* fc1acc = aggC4 + N3 * FL; // 256
  int zcount = (int)((fc1acc + 256) - zbase);

  // zero all accumulators in one launch
  k_zero<<<cdiv(zcount, 256), 256, 0, stream>>>(zbase, zcount);

  // edge counts (dst halves)
  k_count<<<cdiv(E0, 256), 256, 0, stream>>>(e0 + E0, cnt0, E0);
  k_count<<<cdiv(E1, 256), 256, 0, stream>>>(e1 + E1, cnt1, E1);
  k_count<<<cdiv(E2, 256), 256, 0, stream>>>(e2 + E2, cnt2, E2);
  k_count<<<cdiv(E3, 256), 256, 0, stream>>>(e3 + E3, cnt3, E3);

  // ---- level 1: SAGE on e0 (C_in=1), relu, pool 128->64 ----
  k_scatter_s<<<cdiv(E0, 256), 256, 0, stream>>>(e0, e0 + E0, x_image, aggS0, E0);
  k_sage1_node<<<cdiv(N0 * FL, 256), 256, 0, stream>>>(x_image, aggS0, cnt0,
                                                       g1_Wl, g1_bl, g1_Wr, x1, N0);
  k_pool<<<cdiv(N1 * FL, 256), 256, 0, stream>>>(x1, xp1, 128);

  // ---- att block 1 on (4096,48) with e1 ----
  k_att_reduce<<<FL, 256, 0, stream>>>(xp1, N1, stats, stats + 48);
  k_att_vec<<<1, 64, 0, stream>>>(stats, stats + 48, amW[0], amb[0], axW[0], axb[0], stats + 96);
  k_sdot<<<cdiv(N1, 256), 256, 0, stream>>>(xp1, cWl[0], sdot, N1);
  k_scatter_s<<<cdiv(E1, 256), 256, 0, stream>>>(e1, e1 + E1, sdot, aggS1, E1);
  k_gate<<<cdiv(N1 * 64, 256), 256, 0, stream>>>(xp1, stats + 96, aggS1, cnt1, cWr[0], cbl[0], N1);

  // ---- level 2: SAGE on e1, relu, pool 64->32 ----
  k_scatter_v<<<cdiv(E1 * FL, 256), 256, 0, stream>>>(e1, e1 + E1, xp1, aggC2, E1);
  k_sage_node<<<cdiv(N1 * FL, 256), 256, 0, stream>>>(xp1, aggC2, cnt1, g2_Wl, g2_bl, g2_Wr, x2, N1);
  k_pool<<<cdiv(N2 * FL, 256), 256, 0, stream>>>(x2, xp2, 64);

  // ---- att block 2 on (1024,48) with e2 ----
  k_att_reduce<<<FL, 256, 0, stream>>>(xp2, N2, stats, stats + 48);
  k_att_vec<<<1, 64, 0, stream>>>(stats, stats + 48, amW[1], amb[1], axW[1], axb[1], stats + 96);
  k_sdot<<<cdiv(N2, 256), 256, 0, stream>>>(xp2, cWl[1], sdot, N2);
  k_scatter_s<<<cdiv(E2, 256), 256, 0, stream>>>(e2, e2 + E2, sdot, aggS2, E2);
  k_gate<<<cdiv(N2 * 64, 256), 256, 0, stream>>>(xp2, stats + 96, aggS2, cnt2, cWr[1], cbl[1], N2);

  // ---- level 3: SAGE on e2, relu, pool 32->16 ----
  k_scatter_v<<<cdiv(E2 * FL, 256), 256, 0, stream>>>(e2, e2 + E2, xp2, aggC3, E2);
  k_sage_node<<<cdiv(N2 * FL, 256), 256, 0, stream>>>(xp2, aggC3, cnt2, g3_Wl, g3_bl, g3_Wr, x3, N2);
  k_pool<<<cdiv(N3 * FL, 256), 256, 0, stream>>>(x3, xp3, 32);

  // ---- att block 3 on (256,48) with e3 ----
  k_att_reduce<<<FL, 256, 0, stream>>>(xp3, N3, stats, stats + 48);
  k_att_vec<<<1, 64, 0, stream>>>(stats, stats + 48, amW[2], amb[2], axW[2], axb[2], stats + 96);
  k_sdot<<<cdiv(N3, 256), 256, 0, stream>>>(xp3, cWl[2], sdot, N3);
  k_scatter_s<<<cdiv(E3, 256), 256, 0, stream>>>(e3, e3 + E3, sdot, aggS3, E3);
  k_gate<<<cdiv(N3 * 64, 256), 256, 0, stream>>>(xp3, stats + 96, aggS3, cnt3, cWr[2], cbl[2], N3);

  // ---- level 4: SAGE on e3 (no pool) ----
  k_scatter_v<<<cdiv(E3 * FL, 256), 256, 0, stream>>>(e3, e3 + E3, xp3, aggC4, E3);
  k_sage_node<<<cdiv(N3 * FL, 256), 256, 0, stream>>>(xp3, aggC4, cnt3, g4_Wl, g4_bl, g4_Wr, x4, N3);

  // ---- FC head ----
  k_fc1<<<96, 256, 0, stream>>>(x4, fc1_W, fc1acc);
  k_fc_final<<<1, 256, 0, stream>>>(fc1acc, fc1_b, fc2_W, fc2_b, out);

  (void)in_sizes; (void)n_in; (void)out_size; (void)ws_size;
}

// Round 2
// 96.244 us; speedup vs baseline: 1.2694x; 1.2694x over previous
//
#include <hip/hip_runtime.h>
#include <math.h>

#define FL 48

__device__ __forceinline__ float sigmoidf(float v) { return 1.0f / (1.0f + expf(-v)); }

// ---------------- kernels ----------------

__global__ void k_zero(float* __restrict__ p, int n) {
  int i = blockIdx.x * blockDim.x + threadIdx.x;
  if (i < n) p[i] = 0.0f;
}

// fused: degree counts for all 4 edge lists + level-1 scalar scatter (C_in=1)
__global__ __launch_bounds__(256) void k_prep(
    const int* __restrict__ e0, const int* __restrict__ e1,
    const int* __restrict__ e2, const int* __restrict__ e3,
    const float* __restrict__ ximg,
    float* __restrict__ cnt0, float* __restrict__ cnt1,
    float* __restrict__ cnt2, float* __restrict__ cnt3,
    float* __restrict__ aggS0) {
  int g = blockIdx.x * 256 + threadIdx.x;
  if (g < 65536) {
    int d = e0[65536 + g];
    atomicAdd(&cnt0[d], 1.0f);
    atomicAdd(&aggS0[d], ximg[e0[g]]);
  } else if (g < 65536 + 16384) {
    atomicAdd(&cnt1[e1[16384 + (g - 65536)]], 1.0f);
  } else if (g < 65536 + 16384 + 4096) {
    atomicAdd(&cnt2[e2[4096 + (g - 81920)]], 1.0f);
  } else if (g < 65536 + 16384 + 4096 + 1024) {
    atomicAdd(&cnt3[e3[1024 + (g - 86016)]], 1.0f);
  }
}

// level-1 SAGE (C_in=1) + relu + 2x2 maxpool (128 -> 64), writes xp1 (4096,48)
__global__ __launch_bounds__(256) void k_sage1pool(
    const float* __restrict__ x, const float* __restrict__ agg, const float* __restrict__ cnt,
    const float* __restrict__ Wl, const float* __restrict__ bl, const float* __restrict__ Wr,
    float* __restrict__ y) {
  int g = blockIdx.x * 256 + threadIdx.x;
  if (g >= 4096 * FL) return;
  int c = g % FL, m = g / FL;
  int a = m >> 6, b = m & 63;
  float wl = Wl[c], wr = Wr[c], bb = bl[c];
  float best = -INFINITY;
#pragma unroll
  for (int da = 0; da < 2; ++da)
#pragma unroll
    for (int db = 0; db < 2; ++db) {
      int n = (2 * a + da) * 128 + (2 * b + db);
      float mean = agg[n] / fmaxf(cnt[n], 1.0f);
      float v = fmaxf(mean * wl + bb + x[n] * wr, 0.0f);
      best = fmaxf(best, v);
    }
  y[g] = best;
}

// fused: per-channel mean/max reduce (blocks 0..47) + per-node dots x.cWl, x.cWr (rest)
__global__ __launch_bounds__(256) void k_a(
    const float* __restrict__ x, int N,
    const float* __restrict__ cWl, const float* __restrict__ cWr,
    float* __restrict__ mean_out, float* __restrict__ max_out,
    float* __restrict__ dl, float* __restrict__ dr) {
  if (blockIdx.x < FL) {
    int c = blockIdx.x, t = threadIdx.x;
    float s = 0.0f, m = -INFINITY;
    for (int n = t; n < N; n += 256) {
      float v = x[n * FL + c];
      s += v; m = fmaxf(m, v);
    }
    __shared__ float ss[256], sm[256];
    ss[t] = s; sm[t] = m;
    __syncthreads();
    for (int o = 128; o > 0; o >>= 1) {
      if (t < o) { ss[t] += ss[t + o]; sm[t] = fmaxf(sm[t], sm[t + o]); }
      __syncthreads();
    }
    if (t == 0) { mean_out[c] = ss[0] / (float)N; max_out[c] = sm[0]; }
  } else {
    int n = (blockIdx.x - FL) * 256 + threadIdx.x;
    if (n >= N) return;
    float a = 0.0f, b = 0.0f;
    const float* xr = x + n * FL;
    for (int c = 0; c < FL; ++c) { float v = xr[c]; a += v * cWl[c]; b += v * cWr[c]; }
    dl[n] = a; dr[n] = b;
  }
}

// fused: att vector (block 0) + edge scatter of dl into aggS (blocks 1..)
__global__ __launch_bounds__(256) void k_b(
    const float* __restrict__ mean, const float* __restrict__ mx,
    const float* __restrict__ amW, const float* __restrict__ amb,
    const float* __restrict__ axW, const float* __restrict__ axb,
    float* __restrict__ att,
    const int* __restrict__ e, int E, const float* __restrict__ dl,
    float* __restrict__ aggS) {
  if (blockIdx.x == 0) {
    int co = threadIdx.x;
    if (co < FL) {
      float s = amb[co] + axb[co];
      for (int ci = 0; ci < FL; ++ci)
        s += mean[ci] * amW[ci * FL + co] + mx[ci] * axW[ci * FL + co];
      att[co] = sigmoidf(s);
    }
  } else {
    int i = (blockIdx.x - 1) * 256 + threadIdx.x;
    if (i < E) atomicAdd(&aggS[e[E + i]], dl[e[i]]);
  }
}

// gated vector scatter: aggC[dst][c] += x[src][c] * (1 + att[c] + ch[src])
__global__ __launch_bounds__(256) void k_c(
    const int* __restrict__ e, int E,
    const float* __restrict__ x, const float* __restrict__ att,
    const float* __restrict__ aggS, const float* __restrict__ cnt,
    const float* __restrict__ dr, const float* __restrict__ cbl,
    float* __restrict__ aggC) {
  int g = blockIdx.x * 256 + threadIdx.x;
  if (g >= E * FL) return;
  int ei = g / FL, c = g % FL;
  int s = e[ei], d = e[E + ei];
  float ch = sigmoidf(aggS[s] / fmaxf(cnt[s], 1.0f) + cbl[0] + dr[s]);
  float v = x[s * FL + c] * (1.0f + att[c] + ch);
  atomicAdd(&aggC[d * FL + c], v);
}

// gated SAGE 48->48 (+ optional 2x2 maxpool). Gate applied to self term on the fly.
template <int POOL>
__global__ __launch_bounds__(256) void k_d(
    const float* __restrict__ x, const float* __restrict__ aggC, const float* __restrict__ cnt,
    const float* __restrict__ aggS, const float* __restrict__ dr,
    const float* __restrict__ att, const float* __restrict__ cbl,
    const float* __restrict__ Wl, const float* __restrict__ blv, const float* __restrict__ Wr,
    float* __restrict__ y, int H, int Nout) {
  __shared__ float sWl[FL * FL], sWr[FL * FL], sAtt[FL];
  for (int i = threadIdx.x; i < FL * FL; i += 256) { sWl[i] = Wl[i]; sWr[i] = Wr[i]; }
  if (threadIdx.x < FL) sAtt[threadIdx.x] = att[threadIdx.x];
  __syncthreads();
  int g = blockIdx.x * 256 + threadIdx.x;
  if (g >= Nout * FL) return;
  int c = g % FL, m = g / FL;
  float result;
  if (POOL) {
    int Ho = H >> 1;
    int a = m / Ho, b = m % Ho;
    float best = -INFINITY;
#pragma unroll
    for (int da = 0; da < 2; ++da)
#pragma unroll
      for (int db = 0; db < 2; ++db) {
        int n = (2 * a + da) * H + (2 * b + db);
        float rc = 1.0f / fmaxf(cnt[n], 1.0f);
        float ch = sigmoidf(aggS[n] * rc + cbl[0] + dr[n]);
        const float* xr = x + n * FL;
        const float* ar = aggC + n * FL;
        float s = blv[c];
        for (int ci = 0; ci < FL; ++ci)
          s += ar[ci] * rc * sWl[ci * FL + c] + xr[ci] * (1.0f + sAtt[ci] + ch) * sWr[ci * FL + c];
        best = fmaxf(best, fmaxf(s, 0.0f));
      }
    result = best;
  } else {
    int n = m;
    float rc = 1.0f / fmaxf(cnt[n], 1.0f);
    float ch = sigmoidf(aggS[n] * rc + cbl[0] + dr[n]);
    const float* xr = x + n * FL;
    const float* ar = aggC + n * FL;
    float s = blv[c];
    for (int ci = 0; ci < FL; ++ci)
      s += ar[ci] * rc * sWl[ci * FL + c] + xr[ci] * (1.0f + sAtt[ci] + ch) * sWr[ci * FL + c];
    result = fmaxf(s, 0.0f);
  }
  y[g] = result;
}

// FC1 split-K: block b covers k in [b*128,(b+1)*128); thread t = output o
// input k = c*256 + n -> x4[n*48+c]
__global__ __launch_bounds__(256) void k_fc1(const float* __restrict__ x4,
                                             const float* __restrict__ W,
                                             float* __restrict__ acc) {
  __shared__ float xin[128];
  int b = blockIdx.x, t = threadIdx.x;
  int k0 = b * 128;
  if (t < 128) {
    int k = k0 + t;
    int c = k >> 8, n = k & 255;
    xin[t] = x4[n * FL + c];
  }
  __syncthreads();
  float a = 0.0f;
  for (int i = 0; i < 128; ++i) a += xin[i] * W[(size_t)(k0 + i) * 256 + t];
  atomicAdd(&acc[t], a);
}

// fuse fc1 bias+relu, fc2, log_softmax
__global__ void k_fc_final(const float* __restrict__ acc, const float* __restrict__ b1,
                           const float* __restrict__ W2, const float* __restrict__ b2,
                           float* __restrict__ out) {
  __shared__ float a[256];
  __shared__ float logits[10];
  int t = threadIdx.x;
  a[t] = fmaxf(acc[t] + b1[t], 0.0f);
  __syncthreads();
  if (t < 10) {
    float s = b2[t];
    for (int o = 0; o < 256; ++o) s += a[o] * W2[o * 10 + t];
    logits[t] = s;
  }
  __syncthreads();
  if (t == 0) {
    float m = logits[0];
    for (int j = 1; j < 10; ++j) m = fmaxf(m, logits[j]);
    float s = 0.0f;
    for (int j = 0; j < 10; ++j) s += expf(logits[j] - m);
    float ls = logf(s);
    for (int j = 0; j < 10; ++j) out[j] = logits[j] - m - ls;
  }
}

// ---------------- launch ----------------

static inline int cdiv(int a, int b) { return (a + b - 1) / b; }

extern "C" void kernel_launch(void* const* d_in, const int* in_sizes, int n_in,
                              void* d_out, int out_size, void* d_ws, size_t ws_size,
                              hipStream_t stream) {
  const float* x_image = (const float*)d_in[0];
  const int* e0 = (const int*)d_in[1];  // (2, 65536)
  const int* e1 = (const int*)d_in[2];  // (2, 16384)
  const int* e2 = (const int*)d_in[3];  // (2, 4096)
  const int* e3 = (const int*)d_in[4];  // (2, 1024)
  const float* g1_Wl = (const float*)d_in[6];
  const float* g1_bl = (const float*)d_in[7];
  const float* g1_Wr = (const float*)d_in[8];
  const float* gWl[3] = {(const float*)d_in[9], (const float*)d_in[12], (const float*)d_in[15]};
  const float* gbl[3] = {(const float*)d_in[10], (const float*)d_in[13], (const float*)d_in[16]};
  const float* gWr[3] = {(const float*)d_in[11], (const float*)d_in[14], (const float*)d_in[17]};
  const float* amW[3]; const float* amb[3]; const float* axW[3]; const float* axb[3];
  const float* cWl[3]; const float* cbl[3]; const float* cWr[3];
  for (int i = 0; i < 3; ++i) {
    int base = 18 + i * 7;
    amW[i] = (const float*)d_in[base + 0];
    amb[i] = (const float*)d_in[base + 1];
    axW[i] = (const float*)d_in[base + 2];
    axb[i] = (const float*)d_in[base + 3];
    cWl[i] = (const float*)d_in[base + 4];
    cbl[i] = (const float*)d_in[base + 5];
    cWr[i] = (const float*)d_in[base + 6];
  }
  const float* fc1_W = (const float*)d_in[46];
  const float* fc1_b = (const float*)d_in[47];
  const float* fc2_W = (const float*)d_in[48];
  const float* fc2_b = (const float*)d_in[49];
  float* out = (float*)d_out;

  const int N0 = 16384, E1v = 16384;
  const int N1 = 4096, E2v = 4096;
  const int N2 = 1024, E3v = 1024;
  const int N3 = 256;

  // workspace layout (floats)
  float* f = (float*)d_ws;
  float* xp1 = f;                  // 4096*48
  float* xp2 = xp1 + N1 * FL;      // 1024*48
  float* xp3 = xp2 + N2 * FL;      // 256*48
  float* x4  = xp3 + N3 * FL;      // 256*48
  float* dl  = x4 + N3 * FL;       // 4096
  float* dr  = dl + N1;            // 4096
  float* stats = dr + N1;          // 144: mean[48], max[48], att[48]
  float* zbase = stats + 144;
  float* cnt0 = zbase;             // 16384
  float* cnt1 = cnt0 + N0;         // 4096
  float* cnt2 = cnt1 + N1;         // 1024
  float* cnt3 = cnt2 + N2;         // 256
  float* aggS0 = cnt3 + N3;        // 16384
  float* aggS1 = aggS0 + N0;       // 4096
  float* aggS2 = aggS1 + N1;       // 1024
  float* aggS3 = aggS2 + N2;       // 256
  float* aggC2 = aggS3 + N3;       // 4096*48
  float* aggC3 = aggC2 + N1 * FL;  // 1024*48
  float* aggC4 = aggC3 + N2 * FL;  // 256*48
  float* fc1acc = aggC4 + N3 * FL; // 256
  int zcount = (int)((fc1acc + 256) - zbase);

  float* mean = stats;
  float* mx = stats + 48;
  float* att = stats + 96;

  // 1: zero accumulators
  k_zero<<<cdiv(zcount, 256), 256, 0, stream>>>(zbase, zcount);
  // 2: counts x4 + level-1 scatter
  k_prep<<<cdiv(87040, 256), 256, 0, stream>>>(e0, e1, e2, e3, x_image,
                                               cnt0, cnt1, cnt2, cnt3, aggS0);
  // 3: sage1 + pool -> xp1
  k_sage1pool<<<cdiv(N1 * FL, 256), 256, 0, stream>>>(x_image, aggS0, cnt0,
                                                      g1_Wl, g1_bl, g1_Wr, xp1);

  // ---- level 2 with att1 (graph e1) ----
  k_a<<<FL + cdiv(N1, 256), 256, 0, stream>>>(xp1, N1, cWl[0], cWr[0], mean, mx, dl, dr);
  k_b<<<1 + cdiv(E1v, 256), 256, 0, stream>>>(mean, mx, amW[0], amb[0], axW[0], axb[0], att,
                                              e1, E1v, dl, aggS1);
  k_c<<<cdiv(E1v * FL, 256), 256, 0, stream>>>(e1, E1v, xp1, att, aggS1, cnt1, dr, cbl[0], aggC2);
  k_d<1><<<cdiv(N2 * FL, 256), 256, 0, stream>>>(xp1, aggC2, cnt1, aggS1, dr, att, cbl[0],
                                                 gWl[0], gbl[0], gWr[0], xp2, 64, N2);

  // ---- level 3 with att2 (graph e2) ----
  k_a<<<FL + cdiv(N2, 256), 256, 0, stream>>>(xp2, N2, cWl[1], cWr[1], mean, mx, dl, dr);
  k_b<<<1 + cdiv(E2v, 256), 256, 0, stream>>>(mean, mx, amW[1], amb[1], axW[1], axb[1], att,
                                              e2, E2v, dl, aggS2);
  k_c<<<cdiv(E2v * FL, 256), 256, 0, stream>>>(e2, E2v, xp2, att, aggS2, cnt2, dr, cbl[1], aggC3);
  k_d<1><<<cdiv(N3 * FL, 256), 256, 0, stream>>>(xp2, aggC3, cnt2, aggS2, dr, att, cbl[1],
                                                 gWl[1], gbl[1], gWr[1], xp3, 32, N3);

  // ---- level 4 with att3 (graph e3), no pool ----
  k_a<<<FL + cdiv(N3, 256), 256, 0, stream>>>(xp3, N3, cWl[2], cWr[2], mean, mx, dl, dr);
  k_b<<<1 + cdiv(E3v, 256), 256, 0, stream>>>(mean, mx, amW[2], amb[2], axW[2], axb[2], att,
                                              e3, E3v, dl, aggS3);
  k_c<<<cdiv(E3v * FL, 256), 256, 0, stream>>>(e3, E3v, xp3, att, aggS3, cnt3, dr, cbl[2], aggC4);
  k_d<0><<<cdiv(N3 * FL, 256), 256, 0, stream>>>(xp3, aggC4, cnt3, aggS3, dr, att, cbl[2],
                                                 gWl[2], gbl[2], gWr[2], x4, 16, N3);

  // ---- FC head ----
  k_fc1<<<96, 256, 0, stream>>>(x4, fc1_W, fc1acc);
  k_fc_final<<<1, 256, 0, stream>>>(fc1acc, fc1_b, fc2_W, fc2_b, out);

  (void)in_sizes; (void)n_in; (void)out_size; (void)ws_size;
}